// Round 8
// baseline (356.296 us; speedup 1.0000x reference)
//
#include <hip/hip_runtime.h>
#include <hip/hip_bf16.h>

#define NNODES 102400
#define NEDGES 1638400
#define HD 128
#define ZROW_OFF (NNODES * 256)   // byte offset of the zero row within Bb (rows are 256 B)

// histogram build params
#define NB 128                    // histogram blocks
#define NT 512                    // threads per histogram block
#define EPB (NEDGES / NB)         // 12800 edges per block
#define EIT (EPB / NT)            // 25 edges per thread
#define NSLICE 8
#define SLICE (NNODES / NSLICE)   // 12800 nodes per slice -> 50 KB LDS hist

typedef float f32x4 __attribute__((ext_vector_type(4)));
typedef short short8 __attribute__((ext_vector_type(8)));
typedef unsigned short ushort8 __attribute__((ext_vector_type(8)));
typedef unsigned int uint32;

static __device__ __forceinline__ unsigned short f2bf(float v) {
  union { float f; unsigned u; } x; x.f = v;
  unsigned r = x.u + 0x7fffu + ((x.u >> 16) & 1u);   // RNE
  return (unsigned short)(r >> 16);
}
static __device__ __forceinline__ float bflo(uint32 u) { return __uint_as_float(u << 16); }
static __device__ __forceinline__ float bfhi(uint32 u) { return __uint_as_float(u & 0xffff0000u); }

// ---------------- CSR build via LDS histogram (NO global atomics) ----------------
__global__ __launch_bounds__(NT) void k_hist(const int* __restrict__ dst,
                                             unsigned short* __restrict__ blkcnt,
                                             unsigned short* __restrict__ lrank16) {
  __shared__ int hist[SLICE];                 // 50 KB
  const int blk = blockIdx.x, tid = threadIdx.x;
  const int e0 = blk * EPB;
  int dreg[EIT];                              // dst cached in regs, read once
  #pragma unroll
  for (int i = 0; i < EIT; ++i) dreg[i] = dst[e0 + i * NT + tid];

  for (int p = 0; p < NSLICE; ++p) {
    const int lo = p * SLICE;
    for (int i = tid; i < SLICE; i += NT) hist[i] = 0;
    __syncthreads();
    #pragma unroll
    for (int i = 0; i < EIT; ++i) {
      int r = dreg[i] - lo;
      if ((unsigned)r < (unsigned)SLICE) {
        int lr = atomicAdd(&hist[r], 1);
        lrank16[e0 + i * NT + tid] = (unsigned short)lr;
      }
    }
    __syncthreads();
    for (int i = tid; i < SLICE; i += NT)
      blkcnt[(size_t)blk * NNODES + lo + i] = (unsigned short)hist[i];
    __syncthreads();                          // hist reads done before next zeroing
  }
}

// per-node prefix over blocks (in place) + degs/dinv + block-local scan of padded degrees
__global__ __launch_bounds__(256) void k_scan1(unsigned short* __restrict__ blkcnt,
                                               int* __restrict__ rowptr, int* __restrict__ partials,
                                               float* __restrict__ dinv, int* __restrict__ degs) {
  __shared__ int s[256];
  int t = threadIdx.x;
  int i = blockIdx.x * 256 + t;
  int run = 0;
  #pragma unroll 8
  for (int b = 0; b < NB; ++b) {
    size_t idx = (size_t)b * NNODES + i;
    int c = blkcnt[idx];
    blkcnt[idx] = (unsigned short)run;        // exclusive prefix for this node
    run += c;
  }
  degs[i] = run;
  dinv[i] = rsqrtf((float)run + 1.0f);        // +1 self loop
  int vp = (run + 3) & ~3;                    // pad to multiple of 4
  s[t] = vp; __syncthreads();
  for (int off = 1; off < 256; off <<= 1) {
    int x = (t >= off) ? s[t - off] : 0;
    __syncthreads();
    s[t] += x; __syncthreads();
  }
  rowptr[i] = s[t] - vp;                      // local exclusive
  if (t == 255) partials[blockIdx.x] = s[t];
}

__global__ __launch_bounds__(512) void k_scan2(int* __restrict__ partials) {
  __shared__ int s[512];
  int t = threadIdx.x;
  int v = (t < 400) ? partials[t] : 0;
  s[t] = v; __syncthreads();
  for (int off = 1; off < 512; off <<= 1) {
    int x = (t >= off) ? s[t - off] : 0;
    __syncthreads();
    s[t] += x; __syncthreads();
  }
  if (t < 400) partials[t] = s[t] - v;        // exclusive block offsets
}

__global__ __launch_bounds__(256) void k_scan3(int* __restrict__ rowptr, const int* __restrict__ partials,
                                               const int* __restrict__ degs, int* __restrict__ csr) {
  int i = blockIdx.x * 256 + threadIdx.x;
  int base = rowptr[i] + partials[blockIdx.x];
  rowptr[i] = base;
  int v = degs[i];
  int vp = (v + 3) & ~3;
  for (int t = v; t < vp; ++t) csr[base + t] = ZROW_OFF;
  if (i == NNODES - 1) rowptr[NNODES] = base + vp;
}

// part-major decomposition: bid = part*128 + blk  -> all 10 parts of a histogram row
// share bid%8, i.e. land on the SAME XCD (round-robin dispatch) -> that XCD's L2 holds
// just 16 blkcnt rows (3.3 MB) + rowptr. 1280 blocks x 256 thr, 5 edges/thread.
__global__ __launch_bounds__(256) void k_fill(const int* __restrict__ src, const int* __restrict__ dst,
                                              const unsigned short* __restrict__ lrank16,
                                              const int* __restrict__ rowptr,
                                              const unsigned short* __restrict__ blkcnt,
                                              int* __restrict__ csr) {
  int bid = blockIdx.x;
  int part = bid >> 7;                        // 0..9
  int blk  = bid & 127;
  const unsigned short* bc = blkcnt + (size_t)blk * NNODES;
  int e0 = blk * EPB + part * 1280;
  #pragma unroll
  for (int it = 0; it < 5; ++it) {
    int e = e0 + it * 256 + threadIdx.x;
    int s = src[e], d = dst[e];
    csr[rowptr[d] + (int)bc[d] + (int)lrank16[e]] = s * 256;   // byte offset of src row
  }
}

// ---------------- weight prep: WT0 = (W_in@Ws0)^T bf16, bc = b_in@Ws0 f32, WT1 = Ws1^T bf16 ----
__global__ __launch_bounds__(256) void k_prep(const float* __restrict__ W_in, const float* __restrict__ Ws,
                                              const float* __restrict__ b_in,
                                              unsigned short* __restrict__ WT0, unsigned short* __restrict__ WT1,
                                              float* __restrict__ bc) {
  int blk = blockIdx.x, tid = threadIdx.x;
  if (blk < 64) {
    int t = blk * 256 + tid;
    int c = t >> 7, k = t & 127;
    float acc = 0.f;
    #pragma unroll 4
    for (int j = 0; j < 128; ++j) acc += W_in[k * 128 + j] * Ws[j * 128 + c];
    WT0[c * 128 + k] = f2bf(acc);
  } else if (blk == 64) {
    if (tid < 128) {
      float acc = 0.f;
      #pragma unroll 4
      for (int j = 0; j < 128; ++j) acc += b_in[j] * Ws[j * 128 + tid];
      bc[tid] = acc;
    }
  } else {
    int t = (blk - 65) * 256 + tid;
    int c = t >> 7, k = t & 127;
    WT1[c * 128 + k] = f2bf(Ws[128 * 128 + k * 128 + c]);
  }
}

// ---------------- MFMA GEMM: out[r][c] = (in[r][:] @ W[:][c] (+bias)) (*dinv[r]), bf16 out -----
template<bool IN_F32, bool ADD_BIAS, bool SCALE>
__global__ __launch_bounds__(256) void k_gemm(const void* __restrict__ inp, const unsigned short* __restrict__ WT,
                                              const float* __restrict__ bias, const float* __restrict__ dinv,
                                              unsigned short* __restrict__ outp) {
  __shared__ unsigned short sA[128][136];
  __shared__ unsigned short sB[128][136];
  const int tid = threadIdx.x;
  const size_t r0 = (size_t)blockIdx.x * 128;

  #pragma unroll
  for (int i = 0; i < 8; ++i) {
    int f = tid + i * 256;
    int c = f >> 4, u = f & 15;
    *(ushort8*)&sB[c][u * 8] = *(const ushort8*)&WT[(size_t)c * 128 + u * 8];
  }
  if constexpr (IN_F32) {
    const float* in = (const float*)inp;
    #pragma unroll
    for (int i = 0; i < 8; ++i) {
      int f = tid + i * 256;
      int row = f >> 4, u = f & 15;
      const float4 v0 = *(const float4*)&in[(r0 + row) * 128 + u * 8];
      const float4 v1 = *(const float4*)&in[(r0 + row) * 128 + u * 8 + 4];
      ushort8 pk;
      pk[0] = f2bf(v0.x); pk[1] = f2bf(v0.y); pk[2] = f2bf(v0.z); pk[3] = f2bf(v0.w);
      pk[4] = f2bf(v1.x); pk[5] = f2bf(v1.y); pk[6] = f2bf(v1.z); pk[7] = f2bf(v1.w);
      *(ushort8*)&sA[row][u * 8] = pk;
    }
  } else {
    const unsigned short* in = (const unsigned short*)inp;
    #pragma unroll
    for (int i = 0; i < 8; ++i) {
      int f = tid + i * 256;
      int row = f >> 4, u = f & 15;
      *(ushort8*)&sA[row][u * 8] = *(const ushort8*)&in[(r0 + row) * 128 + u * 8];
    }
  }
  __syncthreads();

  const int lane = tid & 63;
  const int wv = tid >> 6;
  const int wr = wv >> 1, wc = wv & 1;
  const int lrow = lane & 15, lg = lane >> 4;

  f32x4 acc[4][4];
  #pragma unroll
  for (int m = 0; m < 4; ++m)
    #pragma unroll
    for (int n = 0; n < 4; ++n)
      acc[m][n] = (f32x4){0.f, 0.f, 0.f, 0.f};

  #pragma unroll
  for (int kt = 0; kt < 4; ++kt) {
    short8 a[4], b[4];
    #pragma unroll
    for (int m = 0; m < 4; ++m)
      a[m] = *(const short8*)&sA[wr * 64 + m * 16 + lrow][kt * 32 + lg * 8];
    #pragma unroll
    for (int n = 0; n < 4; ++n)
      b[n] = *(const short8*)&sB[wc * 64 + n * 16 + lrow][kt * 32 + lg * 8];
    #pragma unroll
    for (int m = 0; m < 4; ++m)
      #pragma unroll
      for (int n = 0; n < 4; ++n)
        acc[m][n] = __builtin_amdgcn_mfma_f32_16x16x32_bf16(a[m], b[n], acc[m][n], 0, 0, 0);
  }

  #pragma unroll
  for (int m = 0; m < 4; ++m) {
    size_t row0 = r0 + wr * 64 + m * 16 + lg * 4;
    float4 dv = {1.f, 1.f, 1.f, 1.f};
    if constexpr (SCALE) dv = *(const float4*)&dinv[row0];
    #pragma unroll
    for (int n = 0; n < 4; ++n) {
      int col = wc * 64 + n * 16 + lrow;
      float bv = ADD_BIAS ? bias[col] : 0.0f;
      f32x4 v = acc[m][n];
      #pragma unroll
      for (int r = 0; r < 4; ++r) {
        float o = v[r] + bv;
        if constexpr (SCALE) o *= ((const float*)&dv)[r];
        outp[(row0 + r) * 128 + col] = f2bf(o);
      }
    }
  }
}

// ---------------- CSR pull-aggregation: out = relu(dinv[n]*(g'[n] + sum g'[src]) + b) -----------
// TWO nodes per wave -> up to 32 outstanding gathers. Rows padded to multiple of 4.
template<bool OUT_F32>
__global__ __launch_bounds__(256) void k_agg(const unsigned short* __restrict__ g, const int* __restrict__ csr,
                                             const int* __restrict__ rowptr, const float* __restrict__ dinv,
                                             const float* __restrict__ bias, void* __restrict__ outp) {
  int w = blockIdx.x * 4 + (threadIdx.x >> 6);   // wave id, 0..51199
  int n0 = 2 * w, n1 = 2 * w + 1;
  int lane = threadIdx.x & 63;
  const char* gb = (const char*)g;
  const int lo4 = lane * 4;

  uint32 sv0 = *(const uint32*)(gb + (size_t)(n0 * 256 + lo4));
  uint32 sv1 = *(const uint32*)(gb + (size_t)(n1 * 256 + lo4));
  float ax0 = bflo(sv0), ay0 = bfhi(sv0);
  float ax1 = bflo(sv1), ay1 = bfhi(sv1);
  int j0 = rowptr[n0], je0 = rowptr[n0 + 1], je1 = rowptr[n0 + 2];
  int j1 = je0;

#define LD(off) (*(const uint32*)(gb + (size_t)(unsigned)((off) + lo4)))
  while (true) {
    bool p0 = (j0 + 16 <= je0), p1 = (j1 + 16 <= je1);
    if (!p0 && !p1) break;
    uint32 q0[16], q1[16];
    if (p0) {
      int4 a = *(const int4*)&csr[j0],     b = *(const int4*)&csr[j0 + 4];
      int4 c = *(const int4*)&csr[j0 + 8], d = *(const int4*)&csr[j0 + 12];
      q0[0]=LD(a.x); q0[1]=LD(a.y); q0[2]=LD(a.z); q0[3]=LD(a.w);
      q0[4]=LD(b.x); q0[5]=LD(b.y); q0[6]=LD(b.z); q0[7]=LD(b.w);
      q0[8]=LD(c.x); q0[9]=LD(c.y); q0[10]=LD(c.z); q0[11]=LD(c.w);
      q0[12]=LD(d.x); q0[13]=LD(d.y); q0[14]=LD(d.z); q0[15]=LD(d.w);
    }
    if (p1) {
      int4 a = *(const int4*)&csr[j1],     b = *(const int4*)&csr[j1 + 4];
      int4 c = *(const int4*)&csr[j1 + 8], d = *(const int4*)&csr[j1 + 12];
      q1[0]=LD(a.x); q1[1]=LD(a.y); q1[2]=LD(a.z); q1[3]=LD(a.w);
      q1[4]=LD(b.x); q1[5]=LD(b.y); q1[6]=LD(b.z); q1[7]=LD(b.w);
      q1[8]=LD(c.x); q1[9]=LD(c.y); q1[10]=LD(c.z); q1[11]=LD(c.w);
      q1[12]=LD(d.x); q1[13]=LD(d.y); q1[14]=LD(d.z); q1[15]=LD(d.w);
    }
    if (p0) {
      #pragma unroll
      for (int t = 0; t < 16; ++t) { ax0 += bflo(q0[t]); ay0 += bfhi(q0[t]); }
      j0 += 16;
    }
    if (p1) {
      #pragma unroll
      for (int t = 0; t < 16; ++t) { ax1 += bflo(q1[t]); ay1 += bfhi(q1[t]); }
      j1 += 16;
    }
  }
  for (; j0 + 4 <= je0; j0 += 4) {
    int4 a = *(const int4*)&csr[j0];
    uint32 u0 = LD(a.x), u1 = LD(a.y), u2 = LD(a.z), u3 = LD(a.w);
    ax0 += bflo(u0) + bflo(u1) + bflo(u2) + bflo(u3);
    ay0 += bfhi(u0) + bfhi(u1) + bfhi(u2) + bfhi(u3);
  }
  for (; j1 + 4 <= je1; j1 += 4) {
    int4 a = *(const int4*)&csr[j1];
    uint32 u0 = LD(a.x), u1 = LD(a.y), u2 = LD(a.z), u3 = LD(a.w);
    ax1 += bflo(u0) + bflo(u1) + bflo(u2) + bflo(u3);
    ay1 += bfhi(u0) + bfhi(u1) + bfhi(u2) + bfhi(u3);
  }
#undef LD

  float d0 = dinv[n0], d1 = dinv[n1];
  float2 b2 = ((const float2*)bias)[lane];
  ax0 = fmaxf(fmaf(ax0, d0, b2.x), 0.0f);
  ay0 = fmaxf(fmaf(ay0, d0, b2.y), 0.0f);
  ax1 = fmaxf(fmaf(ax1, d1, b2.x), 0.0f);
  ay1 = fmaxf(fmaf(ay1, d1, b2.y), 0.0f);
  if constexpr (OUT_F32) {
    ((float2*)outp)[(size_t)n0 * 64 + lane] = make_float2(ax0, ay0);
    ((float2*)outp)[(size_t)n1 * 64 + lane] = make_float2(ax1, ay1);
  } else {
    ((uint32*)outp)[(size_t)n0 * 64 + lane] = ((uint32)f2bf(ay0) << 16) | (uint32)f2bf(ax0);
    ((uint32*)outp)[(size_t)n1 * 64 + lane] = ((uint32)f2bf(ay1) << 16) | (uint32)f2bf(ax1);
  }
}

extern "C" void kernel_launch(void* const* d_in, const int* in_sizes, int n_in,
                              void* d_out, int out_size, void* d_ws, size_t ws_size,
                              hipStream_t stream) {
  const float* x    = (const float*)d_in[0];
  const int*   ei   = (const int*)d_in[1];
  const float* W_in = (const float*)d_in[3];
  const float* b_in = (const float*)d_in[4];
  const float* Ws   = (const float*)d_in[5];
  const float* bs   = (const float*)d_in[6];
  float* out = (float*)d_out;
  const int* src = ei;
  const int* dst = ei + NEDGES;

  char* ws = (char*)d_ws;
  size_t off = 0;
  auto alloc = [&](size_t bytes) { void* p = ws + off; off = (off + bytes + 255) & ~(size_t)255; return p; };
  unsigned short* Bb  = (unsigned short*)alloc((size_t)NNODES * 128 * 2 + 512);  // +1 zero row
  unsigned short* A   = (unsigned short*)alloc((size_t)NNODES * 128 * 2);
  unsigned short* WT0 = (unsigned short*)alloc((size_t)128 * 128 * 2);
  unsigned short* WT1 = (unsigned short*)alloc((size_t)128 * 128 * 2);
  float* bc      = (float*)alloc(128 * 4);
  int*   rowptr  = (int*)alloc((size_t)(NNODES + 1) * 4);
  int*   partials= (int*)alloc(512 * 4);
  float* dinv    = (float*)alloc((size_t)NNODES * 4);
  int*   degs    = (int*)alloc((size_t)NNODES * 4);
  int*   csr     = (int*)alloc((size_t)(NEDGES + 3 * NNODES) * 4);
  // aliases (lifetimes end at k_fill, before first write of their hosts):
  unsigned short* blkcnt  = (unsigned short*)Bb;  // 26.21 MB; Bb first written by gemm0
  unsigned short* lrank16 = (unsigned short*)A;   // 3.3 MB; A first written by k_agg<false>

  hipMemsetAsync(Bb + (size_t)NNODES * 128, 0, 512, stream);   // zero row (just past blkcnt)
  k_hist <<<NB, NT, 0, stream>>>(dst, blkcnt, lrank16);
  k_scan1<<<NNODES / 256, 256, 0, stream>>>(blkcnt, rowptr, partials, dinv, degs);
  k_scan2<<<1, 512, 0, stream>>>(partials);
  k_scan3<<<NNODES / 256, 256, 0, stream>>>(rowptr, partials, degs, csr);
  k_fill <<<1280, 256, 0, stream>>>(src, dst, lrank16, rowptr, blkcnt, csr);
  k_prep <<<129, 256, 0, stream>>>(W_in, Ws, b_in, WT0, WT1, bc);

  // layer 0 fused transform: g' = dinv .* (x@(W_in@Ws0) + b_in@Ws0)  -> Bb
  k_gemm<true, true, true><<<NNODES / 128, 256, 0, stream>>>(x, WT0, bc, dinv, Bb);
  k_agg<false><<<NNODES / 8, 256, 0, stream>>>(Bb, csr, rowptr, dinv, bs, A);
  // layer 1: g' = dinv .* (h1@Ws1) -> Bb ; out = relu(dinv*(sum) + bs1)
  k_gemm<false, false, true><<<NNODES / 128, 256, 0, stream>>>(A, WT1, nullptr, dinv, Bb);
  k_agg<true><<<NNODES / 8, 256, 0, stream>>>(Bb, csr, rowptr, dinv, bs + 128, out);
}

// Round 9
// 334.190 us; speedup vs baseline: 1.0661x; 1.0661x over previous
//
#include <hip/hip_runtime.h>
#include <hip/hip_bf16.h>

#define NNODES 102400
#define NEDGES 1638400
#define HD 128
#define ZROW_OFF (NNODES * 256)   // byte offset of the zero row within Bb (rows are 256 B)

// histogram build params
#define NB 128                    // histogram blocks
#define NT 512                    // threads per histogram block
#define EPB (NEDGES / NB)         // 12800 edges per block
#define EIT (EPB / NT)            // 25 edges per thread
#define NSLICE 5
#define SLICE (NNODES / NSLICE)   // 20480 nodes per slice -> 80 KB LDS hist

#define SCAN_BLOCKS 400           // 400*256 = NNODES

typedef float f32x4 __attribute__((ext_vector_type(4)));
typedef short short8 __attribute__((ext_vector_type(8)));
typedef unsigned short ushort8 __attribute__((ext_vector_type(8)));
typedef unsigned int uint32;

static __device__ __forceinline__ unsigned short f2bf(float v) {
  union { float f; unsigned u; } x; x.f = v;
  unsigned r = x.u + 0x7fffu + ((x.u >> 16) & 1u);   // RNE
  return (unsigned short)(r >> 16);
}
static __device__ __forceinline__ float bflo(uint32 u) { return __uint_as_float(u << 16); }
static __device__ __forceinline__ float bfhi(uint32 u) { return __uint_as_float(u & 0xffff0000u); }

// ---------------- CSR build via LDS histogram (NO global atomics) ----------------
// Also folds in: gctr zeroing + Bb zero-row init (block 0; disjoint from blkcnt bytes).
__global__ __launch_bounds__(NT) void k_hist(const int* __restrict__ dst,
                                             unsigned short* __restrict__ blkcnt,
                                             unsigned short* __restrict__ lrank16,
                                             int* __restrict__ gctr) {
  __shared__ int hist[SLICE];                 // 80 KB
  const int blk = blockIdx.x, tid = threadIdx.x;
  if (blk == 0) {
    if (tid == 0) *gctr = 0;
    if (tid < 128) ((uint32*)((char*)blkcnt + ZROW_OFF))[tid] = 0;   // zero row
  }
  const int e0 = blk * EPB;
  int dreg[EIT];                              // dst cached in regs, read once
  #pragma unroll
  for (int i = 0; i < EIT; ++i) dreg[i] = dst[e0 + i * NT + tid];

  for (int p = 0; p < NSLICE; ++p) {
    const int lo = p * SLICE;
    for (int i = tid; i < SLICE; i += NT) hist[i] = 0;
    __syncthreads();
    #pragma unroll
    for (int i = 0; i < EIT; ++i) {
      int r = dreg[i] - lo;
      if ((unsigned)r < (unsigned)SLICE) {
        int lr = atomicAdd(&hist[r], 1);
        lrank16[e0 + i * NT + tid] = (unsigned short)lr;
      }
    }
    __syncthreads();
    for (int i = tid; i < SLICE; i += NT)
      blkcnt[(size_t)blk * NNODES + lo + i] = (unsigned short)hist[i];
    __syncthreads();                          // hist reads done before next zeroing
  }
}

// ---------------- fused scan (blkcnt prefix + rowse via atomic base + pads + dinv) + prep tail --
// blocks [0,400): scan; blocks [400,529): weight prep.
__global__ __launch_bounds__(256) void k_scanA(unsigned short* __restrict__ blkcnt,
                                               int2* __restrict__ rowse, float* __restrict__ dinv,
                                               int* __restrict__ csr, int* __restrict__ gctr,
                                               const float* __restrict__ W_in, const float* __restrict__ Ws,
                                               const float* __restrict__ b_in,
                                               unsigned short* __restrict__ WT0,
                                               unsigned short* __restrict__ WT1, float* __restrict__ bc) {
  __shared__ int s[256];
  __shared__ int sbase;
  const int bid = blockIdx.x, t = threadIdx.x;
  if (bid >= SCAN_BLOCKS) {                   // ---- weight prep tail ----
    int blk = bid - SCAN_BLOCKS;
    if (blk < 64) {                           // WT0[c][k] = (W_in@Ws0)[k][c]
      int tt = blk * 256 + t;
      int c = tt >> 7, k = tt & 127;
      float acc = 0.f;
      #pragma unroll 4
      for (int j = 0; j < 128; ++j) acc += W_in[k * 128 + j] * Ws[j * 128 + c];
      WT0[c * 128 + k] = f2bf(acc);
    } else if (blk == 64) {                   // bc = b_in@Ws0
      if (t < 128) {
        float acc = 0.f;
        #pragma unroll 4
        for (int j = 0; j < 128; ++j) acc += b_in[j] * Ws[j * 128 + t];
        bc[t] = acc;
      }
    } else {                                  // WT1[c][k] = Ws1[k][c]
      int tt = (blk - 65) * 256 + t;
      int c = tt >> 7, k = tt & 127;
      WT1[c * 128 + k] = f2bf(Ws[128 * 128 + k * 128 + c]);
    }
    return;
  }
  // ---- scan body ----
  int i = bid * 256 + t;
  int run = 0;
  #pragma unroll 8
  for (int b = 0; b < NB; ++b) {
    size_t idx = (size_t)b * NNODES + i;
    int c = blkcnt[idx];
    blkcnt[idx] = (unsigned short)run;        // exclusive prefix for this node
    run += c;
  }
  dinv[i] = rsqrtf((float)run + 1.0f);        // +1 self loop
  int vp = (run + 3) & ~3;                    // pad to multiple of 4
  s[t] = vp; __syncthreads();
  for (int off = 1; off < 256; off <<= 1) {
    int x = (t >= off) ? s[t - off] : 0;
    __syncthreads();
    s[t] += x; __syncthreads();
  }
  if (t == 255) sbase = atomicAdd(gctr, s[255]);   // block base (arrival order - safe: see note)
  __syncthreads();
  int base = sbase + s[t] - vp;
  rowse[i] = make_int2(base, base + vp);
  for (int q = run; q < vp; ++q) csr[base + q] = ZROW_OFF;
}

// part-major: all 10 parts of a histogram row share bid%8 -> same XCD L2 holds 16 blkcnt rows.
__global__ __launch_bounds__(256) void k_fill(const int* __restrict__ src, const int* __restrict__ dst,
                                              const unsigned short* __restrict__ lrank16,
                                              const int2* __restrict__ rowse,
                                              const unsigned short* __restrict__ blkcnt,
                                              int* __restrict__ csr) {
  int bid = blockIdx.x;
  int part = bid >> 7;                        // 0..9
  int blk  = bid & 127;
  const unsigned short* bc = blkcnt + (size_t)blk * NNODES;
  int e0 = blk * EPB + part * 1280;
  #pragma unroll
  for (int it = 0; it < 5; ++it) {
    int e = e0 + it * 256 + threadIdx.x;
    int s = src[e], d = dst[e];
    csr[rowse[d].x + (int)bc[d] + (int)lrank16[e]] = s * 256;   // byte offset of src row
  }
}

// ---------------- MFMA GEMM: out[r][c] = (in[r][:] @ W[:][c] (+bias)) (*dinv[r]), bf16 out -----
template<bool IN_F32, bool ADD_BIAS, bool SCALE>
__global__ __launch_bounds__(256) void k_gemm(const void* __restrict__ inp, const unsigned short* __restrict__ WT,
                                              const float* __restrict__ bias, const float* __restrict__ dinv,
                                              unsigned short* __restrict__ outp) {
  __shared__ unsigned short sA[128][136];
  __shared__ unsigned short sB[128][136];
  const int tid = threadIdx.x;
  const size_t r0 = (size_t)blockIdx.x * 128;

  #pragma unroll
  for (int i = 0; i < 8; ++i) {
    int f = tid + i * 256;
    int c = f >> 4, u = f & 15;
    *(ushort8*)&sB[c][u * 8] = *(const ushort8*)&WT[(size_t)c * 128 + u * 8];
  }
  if constexpr (IN_F32) {
    const float* in = (const float*)inp;
    #pragma unroll
    for (int i = 0; i < 8; ++i) {
      int f = tid + i * 256;
      int row = f >> 4, u = f & 15;
      const float4 v0 = *(const float4*)&in[(r0 + row) * 128 + u * 8];
      const float4 v1 = *(const float4*)&in[(r0 + row) * 128 + u * 8 + 4];
      ushort8 pk;
      pk[0] = f2bf(v0.x); pk[1] = f2bf(v0.y); pk[2] = f2bf(v0.z); pk[3] = f2bf(v0.w);
      pk[4] = f2bf(v1.x); pk[5] = f2bf(v1.y); pk[6] = f2bf(v1.z); pk[7] = f2bf(v1.w);
      *(ushort8*)&sA[row][u * 8] = pk;
    }
  } else {
    const unsigned short* in = (const unsigned short*)inp;
    #pragma unroll
    for (int i = 0; i < 8; ++i) {
      int f = tid + i * 256;
      int row = f >> 4, u = f & 15;
      *(ushort8*)&sA[row][u * 8] = *(const ushort8*)&in[(r0 + row) * 128 + u * 8];
    }
  }
  __syncthreads();

  const int lane = tid & 63;
  const int wv = tid >> 6;
  const int wr = wv >> 1, wc = wv & 1;
  const int lrow = lane & 15, lg = lane >> 4;

  f32x4 acc[4][4];
  #pragma unroll
  for (int m = 0; m < 4; ++m)
    #pragma unroll
    for (int n = 0; n < 4; ++n)
      acc[m][n] = (f32x4){0.f, 0.f, 0.f, 0.f};

  #pragma unroll
  for (int kt = 0; kt < 4; ++kt) {
    short8 a[4], b[4];
    #pragma unroll
    for (int m = 0; m < 4; ++m)
      a[m] = *(const short8*)&sA[wr * 64 + m * 16 + lrow][kt * 32 + lg * 8];
    #pragma unroll
    for (int n = 0; n < 4; ++n)
      b[n] = *(const short8*)&sB[wc * 64 + n * 16 + lrow][kt * 32 + lg * 8];
    #pragma unroll
    for (int m = 0; m < 4; ++m)
      #pragma unroll
      for (int n = 0; n < 4; ++n)
        acc[m][n] = __builtin_amdgcn_mfma_f32_16x16x32_bf16(a[m], b[n], acc[m][n], 0, 0, 0);
  }

  #pragma unroll
  for (int m = 0; m < 4; ++m) {
    size_t row0 = r0 + wr * 64 + m * 16 + lg * 4;
    float4 dv = {1.f, 1.f, 1.f, 1.f};
    if constexpr (SCALE) dv = *(const float4*)&dinv[row0];
    #pragma unroll
    for (int n = 0; n < 4; ++n) {
      int col = wc * 64 + n * 16 + lrow;
      float bv = ADD_BIAS ? bias[col] : 0.0f;
      f32x4 v = acc[m][n];
      #pragma unroll
      for (int r = 0; r < 4; ++r) {
        float o = v[r] + bv;
        if constexpr (SCALE) o *= ((const float*)&dv)[r];
        outp[(row0 + r) * 128 + col] = f2bf(o);
      }
    }
  }
}

// ---------------- CSR pull-aggregation: out = relu(dinv[n]*(g'[n] + sum g'[src]) + b) -----------
// csr holds byte offsets; rows padded to multiple of 4 with zero-row entries.
template<bool OUT_F32>
__global__ __launch_bounds__(256) void k_agg(const unsigned short* __restrict__ g, const int* __restrict__ csr,
                                             const int2* __restrict__ rowse, const float* __restrict__ dinv,
                                             const float* __restrict__ bias, void* __restrict__ outp) {
  int n = blockIdx.x * 4 + (threadIdx.x >> 6);
  int lane = threadIdx.x & 63;
  const char* gb = (const char*)g;
  const int lo4 = lane * 4;

  uint32 sv = *(const uint32*)(gb + (size_t)(n * 256 + lo4));
  float accx = bflo(sv), accy = bfhi(sv);
  int2 se = rowse[n];
  int j = se.x, je = se.y;

#define LD(off) (*(const uint32*)(gb + (size_t)(unsigned)((off) + lo4)))
  for (; j + 16 <= je; j += 16) {
    int4 c0 = *(const int4*)&csr[j];
    int4 c1 = *(const int4*)&csr[j + 4];
    int4 c2 = *(const int4*)&csr[j + 8];
    int4 c3 = *(const int4*)&csr[j + 12];
    uint32 q0 = LD(c0.x), q1 = LD(c0.y), q2 = LD(c0.z), q3 = LD(c0.w);
    uint32 q4 = LD(c1.x), q5 = LD(c1.y), q6 = LD(c1.z), q7 = LD(c1.w);
    uint32 q8 = LD(c2.x), q9 = LD(c2.y), qa = LD(c2.z), qb = LD(c2.w);
    uint32 qc = LD(c3.x), qd = LD(c3.y), qe = LD(c3.z), qf = LD(c3.w);
    accx += bflo(q0) + bflo(q1) + bflo(q2) + bflo(q3)
          + bflo(q4) + bflo(q5) + bflo(q6) + bflo(q7)
          + bflo(q8) + bflo(q9) + bflo(qa) + bflo(qb)
          + bflo(qc) + bflo(qd) + bflo(qe) + bflo(qf);
    accy += bfhi(q0) + bfhi(q1) + bfhi(q2) + bfhi(q3)
          + bfhi(q4) + bfhi(q5) + bfhi(q6) + bfhi(q7)
          + bfhi(q8) + bfhi(q9) + bfhi(qa) + bfhi(qb)
          + bfhi(qc) + bfhi(qd) + bfhi(qe) + bfhi(qf);
  }
  if (j + 8 <= je) {
    int4 c0 = *(const int4*)&csr[j];
    int4 c1 = *(const int4*)&csr[j + 4];
    uint32 q0 = LD(c0.x), q1 = LD(c0.y), q2 = LD(c0.z), q3 = LD(c0.w);
    uint32 q4 = LD(c1.x), q5 = LD(c1.y), q6 = LD(c1.z), q7 = LD(c1.w);
    accx += bflo(q0) + bflo(q1) + bflo(q2) + bflo(q3)
          + bflo(q4) + bflo(q5) + bflo(q6) + bflo(q7);
    accy += bfhi(q0) + bfhi(q1) + bfhi(q2) + bfhi(q3)
          + bfhi(q4) + bfhi(q5) + bfhi(q6) + bfhi(q7);
    j += 8;
  }
  if (j + 4 <= je) {
    int4 c0 = *(const int4*)&csr[j];
    uint32 q0 = LD(c0.x), q1 = LD(c0.y), q2 = LD(c0.z), q3 = LD(c0.w);
    accx += bflo(q0) + bflo(q1) + bflo(q2) + bflo(q3);
    accy += bfhi(q0) + bfhi(q1) + bfhi(q2) + bfhi(q3);
  }
#undef LD

  float dn = dinv[n];
  float2 b2 = ((const float2*)bias)[lane];
  accx = fmaxf(fmaf(accx, dn, b2.x), 0.0f);
  accy = fmaxf(fmaf(accy, dn, b2.y), 0.0f);
  if constexpr (OUT_F32) {
    ((float2*)outp)[(size_t)n * 64 + lane] = make_float2(accx, accy);
  } else {
    uint32 pk = ((uint32)f2bf(accy) << 16) | (uint32)f2bf(accx);
    ((uint32*)outp)[(size_t)n * 64 + lane] = pk;
  }
}

extern "C" void kernel_launch(void* const* d_in, const int* in_sizes, int n_in,
                              void* d_out, int out_size, void* d_ws, size_t ws_size,
                              hipStream_t stream) {
  const float* x    = (const float*)d_in[0];
  const int*   ei   = (const int*)d_in[1];
  const float* W_in = (const float*)d_in[3];
  const float* b_in = (const float*)d_in[4];
  const float* Ws   = (const float*)d_in[5];
  const float* bs   = (const float*)d_in[6];
  float* out = (float*)d_out;
  const int* src = ei;
  const int* dst = ei + NEDGES;

  char* ws = (char*)d_ws;
  size_t off = 0;
  auto alloc = [&](size_t bytes) { void* p = ws + off; off = (off + bytes + 255) & ~(size_t)255; return p; };
  unsigned short* Bb  = (unsigned short*)alloc((size_t)NNODES * 128 * 2 + 512);  // +1 zero row
  unsigned short* A   = (unsigned short*)alloc((size_t)NNODES * 128 * 2);
  unsigned short* WT0 = (unsigned short*)alloc((size_t)128 * 128 * 2);
  unsigned short* WT1 = (unsigned short*)alloc((size_t)128 * 128 * 2);
  float* bc      = (float*)alloc(128 * 4);
  int2*  rowse   = (int2*)alloc((size_t)NNODES * 8);
  int*   gctr    = (int*)alloc(256);
  float* dinv    = (float*)alloc((size_t)NNODES * 4);
  int*   csr     = (int*)alloc((size_t)(NEDGES + 3 * NNODES) * 4);
  // aliases (lifetimes end at k_fill, before first write of their hosts):
  unsigned short* blkcnt  = (unsigned short*)Bb;  // 26.21 MB; Bb first written by gemm0
  unsigned short* lrank16 = (unsigned short*)A;   // 3.3 MB; A first written by k_agg<false>

  // 7 dispatches total; no memsets (k_hist block 0 zeroes gctr + Bb zero-row).
  k_hist <<<NB, NT, 0, stream>>>(dst, blkcnt, lrank16, gctr);
  k_scanA<<<SCAN_BLOCKS + 129, 256, 0, stream>>>(blkcnt, rowse, dinv, csr, gctr,
                                                 W_in, Ws, b_in, WT0, WT1, bc);
  k_fill <<<1280, 256, 0, stream>>>(src, dst, lrank16, rowse, blkcnt, csr);

  // layer 0 fused transform: g' = dinv .* (x@(W_in@Ws0) + b_in@Ws0)  -> Bb
  k_gemm<true, true, true><<<NNODES / 128, 256, 0, stream>>>(x, WT0, bc, dinv, Bb);
  k_agg<false><<<NNODES / 4, 256, 0, stream>>>(Bb, csr, rowse, dinv, bs, A);
  // layer 1: g' = dinv .* (h1@Ws1) -> Bb ; out = relu(dinv*(sum) + bs1)
  k_gemm<false, false, true><<<NNODES / 128, 256, 0, stream>>>(A, WT1, nullptr, dinv, Bb);
  k_agg<true><<<NNODES / 4, 256, 0, stream>>>(Bb, csr, rowse, dinv, bs + 128, out);
}